// Round 3
// baseline (251.821 us; speedup 1.0000x reference)
//
#include <hip/hip_runtime.h>
#include <stdint.h>

typedef unsigned short u16;

#define MTOK 4096
#define CIN  3072
#define COUT 3072
#define RANK 32
#define KT48 48
#define RS   3136       // row stride for xdq/wdq (6272 B: gcd with 4096 = 128 -> good HBM channel spread)
#define LKSPLIT 16
#define LKC (CIN/LKSPLIT)   // 192 = 3 k-tiles

// Workspace:
//   xdq:     (MTOK, RS) bf16    quantized activations (cols 0..3071 valid)
//   wdq:     (COUT, RS) bf16    dequantized weights
//   pu_bf:   (COUT, RANK) bf16  proj_up cast
//   lora_bf: (MTOK, RANK) bf16  reduced lora activations
//   lp:      (LKSPLIT, MTOK, RANK) f32  lora K-split partials (deterministic)

typedef __attribute__((ext_vector_type(8))) short bf16x8;
typedef __attribute__((ext_vector_type(4))) float f32x4;

__device__ __forceinline__ u16 f2bf(float f) {
  union { float f; unsigned u; } v; v.f = f;
  unsigned r = v.u + 0x7FFFu + ((v.u >> 16) & 1u);  // RNE
  return (u16)(r >> 16);
}

__device__ __forceinline__ void gload_lds16(const void* g, void* l) {
  __builtin_amdgcn_global_load_lds(
      (const __attribute__((address_space(1))) unsigned int*)g,
      (__attribute__((address_space(3))) unsigned int*)l, 16, 0, 0);
}

__device__ __forceinline__ float quant1(float xs, float ascale, float qd) {
  float q = rintf(xs / qd);                      // jnp.round = RNE, exact IEEE div
  q = fminf(fmaxf(q, -8.f), 7.f);
  return q * ascale;
}

// ---------------------------------------------------------------------------
// R2 split: the monolithic prep (512 heavy lora blocks + 3072 light wdq
// blocks in one grid) convoyed — heavy blocks serialized 2 rounds/CU while
// light blocks drained early. Split into three pure streaming kernels, each
// with uniform per-block work and full-grid spread. Math is op-for-op
// identical to the fused version -> bitwise-identical outputs.
// ---------------------------------------------------------------------------

// Weight dequant rows + pu_bf cast. 3072 blocks x 256.
__global__ __launch_bounds__(256) void wdq_kernel(
    const int* __restrict__ qw, const float* __restrict__ wsc,
    const float* __restrict__ pu, u16* __restrict__ wdq, u16* __restrict__ pu_bf)
{
  const int o = blockIdx.x;
  const int t = threadIdx.x;
  const int4* qrow = (const int4*)(qw + (size_t)o * CIN);
  u16* orow = wdq + (size_t)o * RS;
#pragma unroll
  for (int p = 0; p < 3; ++p) {
    const int c4 = p * 256 + t;
    const int g = (c4 * 4) >> 6;
    const float ws = wsc[g * COUT + o];    // wscales is (G, C_out)
    const int4 qv = qrow[c4];
    ushort4 ov;
    ov.x = f2bf((float)(qv.x - 8) * ws);
    ov.y = f2bf((float)(qv.y - 8) * ws);
    ov.z = f2bf((float)(qv.z - 8) * ws);
    ov.w = f2bf((float)(qv.w - 8) * ws);
    ((ushort4*)orow)[c4] = ov;
  }
  if (t < RANK) pu_bf[(size_t)o * RANK + t] = f2bf(pu[(size_t)o * RANK + t]);
}

// Activation smoothing + per-group int4 quant -> xdq (bf16 dequantized).
// 1024 blocks x 256: block = (64-row m-panel) x (192-col K-chunk); 16-lane
// subgroups own one 64-wide quant group per row. No LDS, no barriers.
__global__ __launch_bounds__(256) void quant_kernel(
    const float* __restrict__ x, const float* __restrict__ smooth,
    u16* __restrict__ xdq)
{
  const int b = blockIdx.x;
  const int t = threadIdx.x;
  const int m0 = (b >> 4) * 64;         // 64 m-panels of 64 rows
  const int kblk = b & 15;              // 16 K-chunks of 192
  const int col = (t & 15) * 4;
#pragma unroll
  for (int kt = 0; kt < 3; ++kt) {
    const int k0 = kblk * LKC + kt * 64;
#pragma unroll
    for (int it = 0; it < 4; ++it) {
      const int row = m0 + it * 16 + (t >> 4);
      const float4 xv = *(const float4*)(x + (size_t)row * CIN + k0 + col);
      const float4 sv = *(const float4*)(smooth + k0 + col);
      const float xs0 = xv.x / sv.x, xs1 = xv.y / sv.y;
      const float xs2 = xv.z / sv.z, xs3 = xv.w / sv.w;
      float a = fmaxf(fmaxf(fabsf(xs0), fabsf(xs1)), fmaxf(fabsf(xs2), fabsf(xs3)));
#pragma unroll
      for (int off = 1; off < 16; off <<= 1) a = fmaxf(a, __shfl_xor(a, off));
      const float ascale = a / 7.0f;
      const float qd = fmaxf(ascale, 1e-8f);
      ushort4 oq;
      oq.x = f2bf(quant1(xs0, ascale, qd));
      oq.y = f2bf(quant1(xs1, ascale, qd));
      oq.z = f2bf(quant1(xs2, ascale, qd));
      oq.w = f2bf(quant1(xs3, ascale, qd));
      *(ushort4*)(xdq + (size_t)row * RS + k0 + col) = oq;
    }
  }
}

// Low-rank branch: lora partials lp[kblk] = (x/s chunk as bf16) . pd chunk.
// 512 blocks x 256 (32 m-panels of 128 x 16 K-splits). Same math/MFMA order
// as the old fused path -> identical lp.
__global__ __launch_bounds__(256) void lora_kernel(
    const float* __restrict__ x, const float* __restrict__ smooth,
    const float* __restrict__ pd, float* __restrict__ lp)
{
  __shared__ __align__(16) u16 sA[128 * 64];
  __shared__ __align__(16) u16 sB[32 * 64];
  const int b = blockIdx.x;
  const int t = threadIdx.x;
  const int m0 = (b >> 4) * 128;        // 32 m-panels
  const int kblk = b & 15;              // 16 K-splits
  const int wave = t >> 6, lane = t & 63;
  const int lm = lane & 15, lkq = (lane >> 4) * 8;

  f32x4 acc[2][2];
  const f32x4 fz = {0.f, 0.f, 0.f, 0.f};
#pragma unroll
  for (int i = 0; i < 2; ++i)
#pragma unroll
    for (int j = 0; j < 2; ++j) acc[i][j] = fz;

  for (int kt = 0; kt < LKC / 64; ++kt) {
    const int k0 = kblk * LKC + kt * 64;
    const int col = (t & 15) * 4;
#pragma unroll
    for (int it = 0; it < 8; ++it) {
      const int row = it * 16 + (t >> 4);
      const float4 xv = *(const float4*)(x + (size_t)(m0 + row) * CIN + k0 + col);
      const float4 sv = *(const float4*)(smooth + k0 + col);
      ushort4 ov;
      ov.x = f2bf(xv.x / sv.x); ov.y = f2bf(xv.y / sv.y);
      ov.z = f2bf(xv.z / sv.z); ov.w = f2bf(xv.w / sv.w);
      *(ushort4*)&sA[row * 64 + col] = ov;
    }
#pragma unroll
    for (int i = 0; i < 8; ++i) {
      const int idx = i * 256 + t;
      const int k = idx >> 5, r = idx & 31;
      sB[r * 64 + k] = f2bf(pd[(size_t)(k0 + k) * RANK + r]);
    }
    __syncthreads();
#pragma unroll
    for (int kk = 0; kk < 2; ++kk) {
      const int ko = kk * 32 + lkq;
      bf16x8 af[2], bfr[2];
#pragma unroll
      for (int i = 0; i < 2; ++i)
        af[i] = *(const bf16x8*)&sA[(wave * 32 + i * 16 + lm) * 64 + ko];
#pragma unroll
      for (int j = 0; j < 2; ++j)
        bfr[j] = *(const bf16x8*)&sB[(j * 16 + lm) * 64 + ko];
#pragma unroll
      for (int i = 0; i < 2; ++i)
#pragma unroll
        for (int j = 0; j < 2; ++j)
          acc[i][j] = __builtin_amdgcn_mfma_f32_16x16x32_bf16(af[i], bfr[j], acc[i][j], 0, 0, 0);
    }
    __syncthreads();
  }
  float* lpk = lp + (size_t)kblk * MTOK * RANK;
#pragma unroll
  for (int i = 0; i < 2; ++i)
#pragma unroll
    for (int j = 0; j < 2; ++j) {
      const int col = j * 16 + lm;
      const int row0 = m0 + wave * 32 + i * 16 + (lane >> 4) * 4;
#pragma unroll
      for (int r = 0; r < 4; ++r)
        lpk[(size_t)(row0 + r) * RANK + col] = acc[i][j][r];
    }
}

// Reduce lora K-split partials -> bf16 lora_bf (M, 32).
__global__ __launch_bounds__(256) void lora_fix_kernel(
    const float* __restrict__ lp, u16* __restrict__ lora_bf)
{
  const int idx = blockIdx.x * 256 + threadIdx.x;   // MTOK*RANK
  const int m = idx >> 5, c = idx & 31;
  float s = 0.f;
#pragma unroll
  for (int k = 0; k < LKSPLIT; ++k) s += lp[((size_t)k * MTOK + m) * RANK + c];
  lora_bf[(size_t)m * RANK + c] = f2bf(s);
}

// ---------------------------------------------------------------------------
// Main GEMM: 256x256 tile, 8-wave (2M x 4N), BK=64, 8-phase schedule with
// counted vmcnt (T3+T4), LDS slot-swizzle (T2), setprio around MFMA (T5).
//
// LDS: A = [2 buf][2 half][128 rows][64 cols] bf16 (64 KiB), B same -> 128 KiB.
//
// Swizzle (R1 fix, verified: conflicts 2.1e7 -> 0): slot s of row r holds
// global col-chunk c16 = s ^ (r & 7); read slot = (kk*4+q4) ^ (rl&7) ->
// 8 slots x 2 lanes per 16-lane group = 2-way = free.
//
// R2 deepening: stage tile T+2 entirely DURING tile T (was: half during T,
// half during T+1), so every load has 5-7 phases (~800-1100 cy) of cover vs
// the previous 2-6 (~450 cy worst) against ~900 cy HBM latency.
// Slot-release ledger (LDS slot of tile T dead after its read-phase closes):
//   A0,B0: reads issued pre-P0-open, all-waves done by P0-close -> stage @P1
//   B1:    reads pre-P1-open, done by P1-close               -> stage @P2
//   A1:    reads pre-P2-open, done by P2-close               -> stage @P3
// Register reuse (af holds A0 through P0-P1, bf0 through P0+P3, etc.) never
// touches LDS after the read phase, so the early overwrite is safe.
// Boundary wait: vmcnt(8) = exactly T+2's 8 in-flight loads, forcing all of
// T+1 (issued one full tile earlier) complete. Never drains to 0 mid-loop.
// ---------------------------------------------------------------------------

__device__ __forceinline__ void stage_half(const u16* __restrict__ g, u16* lds_base,
                                           int kt, int half, int buf, int t) {
#pragma unroll
  for (int r = 0; r < 2; ++r) {
    const int ld = r * 512 + t;           // 16B-chunk id 0..1023 (8 chunks/row)
    const int row = ld >> 3;              // 0..127 within half
    const int d = ld & 7;                 // dest slot
    const int c16 = d ^ (row & 7);        // source col-chunk (involution)
    gload_lds16(g + (size_t)(half * 128 + row) * RS + kt * 64 + c16 * 8,
                lds_base + buf * 16384 + half * 8192 + ld * 8);
  }
}

#define DSA(buf, mh) \
  _Pragma("unroll") for (int i = 0; i < 4; ++i) { \
    const int rl = wm * 64 + i * 16 + lm; \
    _Pragma("unroll") for (int kk = 0; kk < 2; ++kk) \
      af[i][kk] = *(const bf16x8*)&lds[(buf)*16384 + (mh)*8192 + rl * 64 + \
                    ((((kk << 2) | q4) ^ (rl & 7)) << 3)]; \
  }

#define DSB(buf, nh, BF) \
  _Pragma("unroll") for (int j = 0; j < 2; ++j) { \
    const int rl = wn * 32 + j * 16 + lm; \
    _Pragma("unroll") for (int kk = 0; kk < 2; ++kk) \
      BF[j][kk] = *(const bf16x8*)&lds[32768 + (buf)*16384 + (nh)*8192 + rl * 64 + \
                    ((((kk << 2) | q4) ^ (rl & 7)) << 3)]; \
  }

#define MFMA_Q(mh, nh, BF) \
  __builtin_amdgcn_s_setprio(1); \
  _Pragma("unroll") for (int i = 0; i < 4; ++i) \
  _Pragma("unroll") for (int j = 0; j < 2; ++j) \
  _Pragma("unroll") for (int kk = 0; kk < 2; ++kk) \
    acc[(mh)*4 + i][(nh)*2 + j] = __builtin_amdgcn_mfma_f32_16x16x32_bf16( \
        af[i][kk], BF[j][kk], acc[(mh)*4 + i][(nh)*2 + j], 0, 0, 0); \
  __builtin_amdgcn_s_setprio(0);

#define PH_OPEN() \
  __builtin_amdgcn_sched_barrier(0); \
  __builtin_amdgcn_s_barrier(); \
  asm volatile("s_waitcnt lgkmcnt(0)" ::: "memory"); \
  __builtin_amdgcn_sched_barrier(0)

#define PH_CLOSE() \
  __builtin_amdgcn_sched_barrier(0); \
  __builtin_amdgcn_s_barrier(); \
  __builtin_amdgcn_sched_barrier(0)

#define VM8() asm volatile("s_waitcnt vmcnt(8)" ::: "memory")
#define VM0() asm volatile("s_waitcnt vmcnt(0)" ::: "memory")

// One K-tile (4 phases). S_* = stage statements for tile T+2, VMI = boundary.
#define TILE8(cur, S_A0, S_B0, S_B1, S_A1, VMI) do { \
  DSA(cur, 0); DSB(cur, 0, bf0); \
  PH_OPEN(); MFMA_Q(0, 0, bf0); PH_CLOSE(); \
  DSB(cur, 1, bf1); S_A0; S_B0; \
  PH_OPEN(); MFMA_Q(0, 1, bf1); PH_CLOSE(); \
  DSA(cur, 1); S_B1; \
  PH_OPEN(); MFMA_Q(1, 1, bf1); PH_CLOSE(); \
  S_A1; \
  PH_OPEN(); MFMA_Q(1, 0, bf0); VMI; PH_CLOSE(); \
} while (0)

__global__ __launch_bounds__(512, 2) void gemm_kernel(
    const u16* __restrict__ xdq, const u16* __restrict__ wdq,
    const u16* __restrict__ pu_bf, const u16* __restrict__ lora_bf,
    const float* __restrict__ bias, float* __restrict__ out)
{
  __shared__ __align__(16) u16 lds[65536];   // 128 KiB: A[0..32767], B[32768..]

  const int t = threadIdx.x;
  const int wid = t >> 6, lane = t & 63;
  const int wm = wid >> 2, wn = wid & 3;     // 2M x 4N wave grid
  const int lm = lane & 15, q4 = lane >> 4;

  // XCD-aware swizzle (192 = 8 XCDs * 24): each XCD gets 2 full M-rows of tiles
  const int wg = blockIdx.x;
  const int swz = (wg & 7) * 24 + (wg >> 3);
  const int by = swz / 12, bx = swz % 12;    // by: M-tile 0..15, bx: N-tile 0..11
  const int m0 = by * 256, n0 = bx * 256;

  const u16* Ag = xdq + (size_t)m0 * RS;
  const u16* Bg = wdq + (size_t)n0 * RS;
  u16* ldsB = lds + 32768;

  f32x4 acc[8][4];
  const f32x4 fz = {0.f, 0.f, 0.f, 0.f};
#pragma unroll
  for (int i = 0; i < 8; ++i)
#pragma unroll
    for (int j = 0; j < 4; ++j) acc[i][j] = fz;

  bf16x8 af[4][2], bf0[2][2], bf1[2][2];

  // Prologue: stage T0 (4 halves) then T1 (4 halves); vmcnt(8) forces T0
  // complete while T1's 8 loads stay in flight.
  stage_half(Ag, lds,  0, 0, 0, t);
  stage_half(Bg, ldsB, 0, 0, 0, t);
  stage_half(Bg, ldsB, 0, 1, 0, t);
  stage_half(Ag, lds,  0, 1, 0, t);
  stage_half(Ag, lds,  1, 0, 1, t);
  stage_half(Bg, ldsB, 1, 0, 1, t);
  stage_half(Bg, ldsB, 1, 1, 1, t);
  stage_half(Ag, lds,  1, 1, 1, t);
  VM8();
  __builtin_amdgcn_s_barrier();
  __builtin_amdgcn_sched_barrier(0);

  // Main loop: tiles 0..45; during tile T stage ALL of tile T+2 (same buf).
  for (int T = 0; T < 46; T += 2) {
    TILE8(0,
          stage_half(Ag, lds,  T + 2, 0, 0, t),
          stage_half(Bg, ldsB, T + 2, 0, 0, t),
          stage_half(Bg, ldsB, T + 2, 1, 0, t),
          stage_half(Ag, lds,  T + 2, 1, 0, t),
          VM8());
    TILE8(1,
          stage_half(Ag, lds,  T + 3, 0, 1, t),
          stage_half(Bg, ldsB, T + 3, 0, 1, t),
          stage_half(Bg, ldsB, T + 3, 1, 1, t),
          stage_half(Ag, lds,  T + 3, 1, 1, t),
          VM8());
  }
  // Epilogue: tile 46 (no stages, drain T47's loads), tile 47 (no stages)
  TILE8(0, (void)0, (void)0, (void)0, (void)0, VM0());
  TILE8(1, (void)0, (void)0, (void)0, (void)0, (void)0);

  // ---- lora epilogue: acc += lora_act(256x32) . proj_up(256x32)^T (L2-hot) ----
  bf16x8 bl[4];
#pragma unroll
  for (int b = 0; b < 4; ++b) {
    const int bcol = n0 + (b >> 1) * 128 + wn * 32 + (b & 1) * 16 + lm;
    bl[b] = *(const bf16x8*)(pu_bf + (size_t)bcol * RANK + q4 * 8);
  }
#pragma unroll
  for (int a = 0; a < 8; ++a) {
    const int arow = m0 + (a >> 2) * 128 + wm * 64 + (a & 3) * 16 + lm;
    const bf16x8 al = *(const bf16x8*)(lora_bf + (size_t)arow * RANK + q4 * 8);
#pragma unroll
    for (int b = 0; b < 4; ++b)
      acc[a][b] = __builtin_amdgcn_mfma_f32_16x16x32_bf16(al, bl[b], acc[a][b], 0, 0, 0);
  }

  // store: C/D layout col=lane&15, row=(lane>>4)*4+reg  [m89-verified]
#pragma unroll
  for (int b = 0; b < 4; ++b) {
    const int col = n0 + (b >> 1) * 128 + wn * 32 + (b & 1) * 16 + lm;
    const float bv = bias[col];
#pragma unroll
    for (int a = 0; a < 8; ++a) {
      const int row0 = m0 + (a >> 2) * 128 + wm * 64 + (a & 3) * 16 + q4 * 4;
#pragma unroll
      for (int r = 0; r < 4; ++r)
        out[(size_t)(row0 + r) * COUT + col] = acc[a][b][r] + bv;
    }
  }
}

extern "C" void kernel_launch(void* const* d_in, const int* in_sizes, int n_in,
                              void* d_out, int out_size, void* d_ws, size_t ws_size,
                              hipStream_t stream) {
  const float* x      = (const float*)d_in[0];
  const int*   qw     = (const int*)d_in[1];
  const float* wsc    = (const float*)d_in[2];
  const float* smooth = (const float*)d_in[3];
  const float* pd     = (const float*)d_in[4];
  const float* pu     = (const float*)d_in[5];
  const float* bias   = (const float*)d_in[6];
  float* out = (float*)d_out;

  u16* xdq     = (u16*)d_ws;                               // 4096*3136*2 = 25.7 MB
  u16* wdq     = xdq + (size_t)MTOK * RS;                  // 3072*3136*2 = 19.3 MB
  u16* pu_bf   = wdq + (size_t)COUT * RS;                  // 3072*32*2   = 0.2 MB
  u16* lora_bf = pu_bf + (size_t)COUT * RANK;              // 4096*32*2   = 0.3 MB
  float* lp    = (float*)(lora_bf + (size_t)MTOK * RANK);  // 16*4096*32*4 = 8.4 MB

  wdq_kernel<<<COUT, 256, 0, stream>>>(qw, wsc, pu, wdq, pu_bf);
  quant_kernel<<<1024, 256, 0, stream>>>(x, smooth, xdq);
  lora_kernel<<<512, 256, 0, stream>>>(x, smooth, pd, lp);
  lora_fix_kernel<<<MTOK * RANK / 256, 256, 0, stream>>>(lp, lora_bf);
  gemm_kernel<<<192, 512, 0, stream>>>(
      xdq, wdq, pu_bf, lora_bf, bias, out);
}

// Round 4
// 226.133 us; speedup vs baseline: 1.1136x; 1.1136x over previous
//
#include <hip/hip_runtime.h>
#include <stdint.h>

typedef unsigned short u16;

#define MTOK 4096
#define CIN  3072
#define COUT 3072
#define RANK 32
#define RS   3136       // row stride for xdq/wdq (6272 B: gcd with 4096 = 128 -> good HBM channel spread)
#define LKSPLIT 16
#define LKC (CIN/LKSPLIT)   // 192 = 3 k-tiles
#define KTILES 96           // gemm K-tiles at BK=32

// prep grid: [0, LORA_BLK) fused lora+quant panels, rest wdq rows
#define LORA_BLK (MTOK/128*LKSPLIT)  // 512
#define WDQ_BLK COUT                 // 3072

typedef __attribute__((ext_vector_type(8))) short bf16x8;
typedef __attribute__((ext_vector_type(4))) float f32x4;
typedef __attribute__((ext_vector_type(16))) float f32x16;

__device__ __forceinline__ u16 f2bf(float f) {
  union { float f; unsigned u; } v; v.f = f;
  unsigned r = v.u + 0x7FFFu + ((v.u >> 16) & 1u);  // RNE
  return (u16)(r >> 16);
}

__device__ __forceinline__ void gload_lds16(const void* g, void* l) {
  __builtin_amdgcn_global_load_lds(
      (const __attribute__((address_space(1))) unsigned int*)g,
      (__attribute__((address_space(3))) unsigned int*)l, 16, 0, 0);
}

__device__ __forceinline__ float quant1(float xs, float ascale, float qd) {
  float q = rintf(xs / qd);                      // jnp.round = RNE, exact IEEE div
  q = fminf(fmaxf(q, -8.f), 7.f);
  return q * ascale;
}

// Fused prep (R2 version, reverted: split kernels serialized on the stream and
// cost ~25 us): lora-panel blocks (emit quantized xdq for their chunk — x read
// ONCE) + weight dequant rows.
__global__ __launch_bounds__(256) void prep_kernel(
    const float* __restrict__ x, const float* __restrict__ smooth,
    const int* __restrict__ qw, const float* __restrict__ wsc,
    const float* __restrict__ pd, const float* __restrict__ pu,
    u16* __restrict__ xdq, u16* __restrict__ wdq, u16* __restrict__ pu_bf,
    float* __restrict__ lp)
{
  const int b = blockIdx.x;
  const int t = threadIdx.x;

  if (b < LORA_BLK) {
    __shared__ __align__(16) u16 sA[128 * 64];
    __shared__ __align__(16) u16 sB[32 * 64];
    const int m0 = (b >> 4) * 128;        // 32 m-panels
    const int kblk = b & 15;              // 16 K-splits
    const int wave = t >> 6, lane = t & 63;
    const int lm = lane & 15, lkq = (lane >> 4) * 8;

    f32x4 acc[2][2];
    const f32x4 fz = {0.f, 0.f, 0.f, 0.f};
#pragma unroll
    for (int i = 0; i < 2; ++i)
#pragma unroll
      for (int j = 0; j < 2; ++j) acc[i][j] = fz;

    for (int kt = 0; kt < LKC / 64; ++kt) {
      const int k0 = kblk * LKC + kt * 64;
      const int col = (t & 15) * 4;       // 16 lanes x 4 = one 64-quant-group per row
#pragma unroll
      for (int it = 0; it < 8; ++it) {
        const int row = it * 16 + (t >> 4);
        const float4 xv = *(const float4*)(x + (size_t)(m0 + row) * CIN + k0 + col);
        const float4 sv = *(const float4*)(smooth + k0 + col);
        const float xs0 = xv.x / sv.x, xs1 = xv.y / sv.y;
        const float xs2 = xv.z / sv.z, xs3 = xv.w / sv.w;
        ushort4 ov;
        ov.x = f2bf(xs0); ov.y = f2bf(xs1); ov.z = f2bf(xs2); ov.w = f2bf(xs3);
        *(ushort4*)&sA[row * 64 + col] = ov;
        float a = fmaxf(fmaxf(fabsf(xs0), fabsf(xs1)), fmaxf(fabsf(xs2), fabsf(xs3)));
#pragma unroll
        for (int off = 1; off < 16; off <<= 1) a = fmaxf(a, __shfl_xor(a, off));
        const float ascale = a / 7.0f;
        const float qd = fmaxf(ascale, 1e-8f);
        ushort4 oq;
        oq.x = f2bf(quant1(xs0, ascale, qd));
        oq.y = f2bf(quant1(xs1, ascale, qd));
        oq.z = f2bf(quant1(xs2, ascale, qd));
        oq.w = f2bf(quant1(xs3, ascale, qd));
        *(ushort4*)(xdq + (size_t)(m0 + row) * RS + k0 + col) = oq;
      }
#pragma unroll
      for (int i = 0; i < 8; ++i) {
        const int idx = i * 256 + t;
        const int k = idx >> 5, r = idx & 31;
        sB[r * 64 + k] = f2bf(pd[(size_t)(k0 + k) * RANK + r]);
      }
      __syncthreads();
#pragma unroll
      for (int kk = 0; kk < 2; ++kk) {
        const int ko = kk * 32 + lkq;
        bf16x8 af[2], bfr[2];
#pragma unroll
        for (int i = 0; i < 2; ++i)
          af[i] = *(const bf16x8*)&sA[(wave * 32 + i * 16 + lm) * 64 + ko];
#pragma unroll
        for (int j = 0; j < 2; ++j)
          bfr[j] = *(const bf16x8*)&sB[(j * 16 + lm) * 64 + ko];
#pragma unroll
        for (int i = 0; i < 2; ++i)
#pragma unroll
          for (int j = 0; j < 2; ++j)
            acc[i][j] = __builtin_amdgcn_mfma_f32_16x16x32_bf16(af[i], bfr[j], acc[i][j], 0, 0, 0);
      }
      __syncthreads();
    }
    float* lpk = lp + (size_t)kblk * MTOK * RANK;
#pragma unroll
    for (int i = 0; i < 2; ++i)
#pragma unroll
      for (int j = 0; j < 2; ++j) {
        const int col = j * 16 + lm;
        const int row0 = m0 + wave * 32 + i * 16 + (lane >> 4) * 4;
#pragma unroll
        for (int r = 0; r < 4; ++r)
          lpk[(size_t)(row0 + r) * RANK + col] = acc[i][j][r];
      }
  } else {
    const int o = b - LORA_BLK;
    const int4* qrow = (const int4*)(qw + (size_t)o * CIN);
    u16* orow = wdq + (size_t)o * RS;
#pragma unroll
    for (int p = 0; p < 3; ++p) {
      const int c4 = p * 256 + t;
      const int g = (c4 * 4) >> 6;
      const float ws = wsc[g * COUT + o];    // wscales is (G, C_out)
      const int4 qv = qrow[c4];
      ushort4 ov;
      ov.x = f2bf((float)(qv.x - 8) * ws);
      ov.y = f2bf((float)(qv.y - 8) * ws);
      ov.z = f2bf((float)(qv.z - 8) * ws);
      ov.w = f2bf((float)(qv.w - 8) * ws);
      ((ushort4*)orow)[c4] = ov;
    }
    if (t < RANK) pu_bf[(size_t)o * RANK + t] = f2bf(pu[(size_t)o * RANK + t]);
  }
}

// Reduce lora K-split partials -> bf16 lora_bf (M, 32).
__global__ __launch_bounds__(256) void lora_fix_kernel(
    const float* __restrict__ lp, u16* __restrict__ lora_bf)
{
  const int idx = blockIdx.x * 256 + threadIdx.x;   // MTOK*RANK
  const int m = idx >> 5, c = idx & 31;
  float s = 0.f;
#pragma unroll
  for (int k = 0; k < LKSPLIT; ++k) s += lp[((size_t)k * MTOK + m) * RANK + c];
  lora_bf[(size_t)m * RANK + c] = f2bf(s);
}

// ---------------------------------------------------------------------------
// Main GEMM (R4 restructure): the 8-phase schedule measured 94 us because all
// ds_reads drained (lgkmcnt(0)) BEFORE each MFMA burst — LDS pipe (~2300 cy/
// tile) and MFMA pipe (~2500 cy/tile) ran serially (sum ~= 4400 cy/tile ~= 89
// us, matching measurement). New structure overlaps them:
//
//  - 256x256 tile, 8 waves (2M x 4N), per-wave 128x64.
//  - mfma_f32_32x32x16_bf16 (2382 TF rate vs 2075; half the instructions).
//  - BK=32, K-tiles=96, LDS = 3 rotating buffers x (A 16K + B 16K) = 96 KiB.
//    3-deep rotation lets tile T+2 stage while tile T is read (disjoint buf).
//  - 2 k-steps/tile, operand sets P/Q double-buffered in registers: reads for
//    step s+1 are issued BEFORE the MFMAs of step s -> compiler emits counted
//    lgkmcnt and the LDS pipe runs under the MFMA burst.
//  - ONE barrier + one counted vmcnt per tile:
//      [stage T+2 -> buf(T+2)%3] [read s1] [MFMA s0] [vmcnt(4)] [barrier]
//      [read s0 of T+1 from buf(T+1)%3] [MFMA s1]
//    vmcnt(4) leaves T+2's 4 loads in flight, forces T+1 complete; the
//    barrier then makes T+1 visible to all waves BEFORE its first reads.
//    Stage of T+2 overwrites buf of T-1, whose reads all drained before the
//    shared barrier inside tile T-1 (reads issue pre-barrier, stage lands
//    >=300cy post-barrier).
//
// Bank math at BK=32 (64 B rows = HALF a 32-bank wrap): bank granule =
// {row&1, slot[1:0]} (3 bits). Swizzle slot' = slot ^ ((row>>1)&3): within a
// 16-lane group rows r0..r0+15 enumerate all 8 granules twice -> 2-way = free.
// Stage applies the same involution to the global SOURCE col-chunk (LDS dest
// stays linear: wave-uniform base + lane*16, required by global_load_lds).
// ---------------------------------------------------------------------------

__device__ __forceinline__ void stage_tile(const u16* __restrict__ gA,
                                           const u16* __restrict__ gB,
                                           u16* ldsbuf, int kt, int t) {
#pragma unroll
  for (int r = 0; r < 2; ++r) {
    const int id = r * 512 + t;          // 16B chunk id 0..1023 (4 chunks/row)
    const int row = id >> 2;             // 0..255
    const int l = id & 3;                // dest slot
    const int src = l ^ ((row >> 1) & 3);  // source col-chunk (involution)
    gload_lds16(gA + (size_t)row * RS + kt * 32 + src * 8, ldsbuf + id * 8);
    gload_lds16(gB + (size_t)row * RS + kt * 32 + src * 8, ldsbuf + 8192 + id * 8);
  }
}

#define RD_A(DST, BUF, S) \
  _Pragma("unroll") for (int i_ = 0; i_ < 4; ++i_) { \
    const int rr = wm * 128 + i_ * 32 + l31; \
    const int ph = (((S) << 1) | hi) ^ ((rr >> 1) & 3); \
    DST[i_] = *(const bf16x8*)&lds[(BUF) * 16384 + rr * 32 + ph * 8]; \
  }

#define RD_B(DST, BUF, S) \
  _Pragma("unroll") for (int j_ = 0; j_ < 2; ++j_) { \
    const int rr = wn * 64 + j_ * 32 + l31; \
    const int ph = (((S) << 1) | hi) ^ ((rr >> 1) & 3); \
    DST[j_] = *(const bf16x8*)&lds[(BUF) * 16384 + 8192 + rr * 32 + ph * 8]; \
  }

#define MM(A_, B_) \
  __builtin_amdgcn_s_setprio(1); \
  _Pragma("unroll") for (int i_ = 0; i_ < 4; ++i_) \
  _Pragma("unroll") for (int j_ = 0; j_ < 2; ++j_) \
    acc[i_][j_] = __builtin_amdgcn_mfma_f32_32x32x16_bf16(A_[i_], B_[j_], acc[i_][j_], 0, 0, 0); \
  __builtin_amdgcn_s_setprio(0);

#define VM4() asm volatile("s_waitcnt vmcnt(4)" ::: "memory")
#define VM0() asm volatile("s_waitcnt vmcnt(0)" ::: "memory")

// One K-tile. CB=current buf, NB=next-tile buf, SB=stage buf ((t+2)%3).
#define TILE(T_, CB, NB, SB, DOSTAGE, DONEXT, VMW) do { \
  if (DOSTAGE) stage_tile(Ag, Bg, lds + (SB) * 16384, (T_) + 2, tid); \
  __builtin_amdgcn_sched_barrier(0); \
  RD_A(aQ, CB, 1); RD_B(bQ, CB, 1); \
  __builtin_amdgcn_sched_barrier(0); \
  MM(aP, bP); \
  __builtin_amdgcn_sched_barrier(0); \
  VMW; \
  if (DONEXT) { \
    __builtin_amdgcn_s_barrier(); \
    __builtin_amdgcn_sched_barrier(0); \
    RD_A(aP, NB, 0); RD_B(bP, NB, 0); \
    __builtin_amdgcn_sched_barrier(0); \
  } \
  MM(aQ, bQ); \
  __builtin_amdgcn_sched_barrier(0); \
} while (0)

__global__ __launch_bounds__(512, 2) void gemm_kernel(
    const u16* __restrict__ xdq, const u16* __restrict__ wdq,
    const u16* __restrict__ pu_bf, const u16* __restrict__ lora_bf,
    const float* __restrict__ bias, float* __restrict__ out)
{
  __shared__ __align__(16) u16 lds[49152];   // 96 KiB: 3 bufs x (A 16K | B 16K)

  const int tid = threadIdx.x;
  const int wid = tid >> 6, lane = tid & 63;
  const int wm = wid >> 2, wn = wid & 3;     // 2M x 4N wave grid
  const int l31 = lane & 31, hi = lane >> 5;

  // XCD-aware swizzle (192 = 8 XCDs * 24): each XCD gets 2 full M-rows of tiles
  const int wg = blockIdx.x;
  const int swz = (wg & 7) * 24 + (wg >> 3);
  const int by = swz / 12, bx = swz % 12;    // by: M-tile 0..15, bx: N-tile 0..11
  const int m0 = by * 256, n0 = bx * 256;

  const u16* Ag = xdq + (size_t)m0 * RS;
  const u16* Bg = wdq + (size_t)n0 * RS;

  f32x16 acc[4][2];
#pragma unroll
  for (int i = 0; i < 4; ++i)
#pragma unroll
    for (int j = 0; j < 2; ++j) acc[i][j] = (f32x16)(0.0f);

  bf16x8 aP[4], bP[2], aQ[4], bQ[2];

  // Prologue: stage T0->buf0, T1->buf1; vmcnt(4) forces T0 (leaves T1 in
  // flight); barrier; read T0's k-step 0 into P.
  stage_tile(Ag, Bg, lds, 0, tid);
  stage_tile(Ag, Bg, lds + 16384, 1, tid);
  VM4();
  __builtin_amdgcn_s_barrier();
  __builtin_amdgcn_sched_barrier(0);
  RD_A(aP, 0, 0); RD_B(bP, 0, 0);
  __builtin_amdgcn_sched_barrier(0);

  // Main loop: tiles 0..92 (buf indices static via x3 unroll)
  for (int T = 0; T < 93; T += 3) {
    TILE(T + 0, 0, 1, 2, 1, 1, VM4());
    TILE(T + 1, 1, 2, 0, 1, 1, VM4());
    TILE(T + 2, 2, 0, 1, 1, 1, VM4());
  }
  // Epilogue tiles 93 (stages 95), 94 (drain), 95 (no barrier/next)
  TILE(93, 0, 1, 2, 1, 1, VM4());
  TILE(94, 1, 2, 0, 0, 1, VM0());
  TILE(95, 2, 0, 1, 0, 0, (void)0);

  // ---- lora epilogue: acc += lora_act(256x32) . proj_up(256x32)^T (L2-hot) ----
#pragma unroll
  for (int ks = 0; ks < 2; ++ks) {
    bf16x8 bl[2], al[4];
#pragma unroll
    for (int j = 0; j < 2; ++j) {
      const int col = n0 + wn * 64 + j * 32 + l31;
      bl[j] = *(const bf16x8*)(pu_bf + (size_t)col * RANK + ks * 16 + hi * 8);
    }
#pragma unroll
    for (int i = 0; i < 4; ++i) {
      const int arow = m0 + wm * 128 + i * 32 + l31;
      al[i] = *(const bf16x8*)(lora_bf + (size_t)arow * RANK + ks * 16 + hi * 8);
    }
#pragma unroll
    for (int i = 0; i < 4; ++i)
#pragma unroll
      for (int j = 0; j < 2; ++j)
        acc[i][j] = __builtin_amdgcn_mfma_f32_32x32x16_bf16(al[i], bl[j], acc[i][j], 0, 0, 0);
  }

  // store: 32x32 C/D layout col=lane&31, row=(reg&3)+8*(reg>>2)+4*(lane>>5)
  // [m74/m101-verified]
#pragma unroll
  for (int j = 0; j < 2; ++j) {
    const int col = n0 + wn * 64 + j * 32 + l31;
    const float bv = bias[col];
#pragma unroll
    for (int i = 0; i < 4; ++i) {
      const int rbase = m0 + wm * 128 + i * 32 + 4 * hi;
#pragma unroll
      for (int reg = 0; reg < 16; ++reg) {
        const int row = rbase + (reg & 3) + 8 * (reg >> 2);
        out[(size_t)row * COUT + col] = acc[i][j][reg] + bv;
      }
    }
  }
}

extern "C" void kernel_launch(void* const* d_in, const int* in_sizes, int n_in,
                              void* d_out, int out_size, void* d_ws, size_t ws_size,
                              hipStream_t stream) {
  const float* x      = (const float*)d_in[0];
  const int*   qw     = (const int*)d_in[1];
  const float* wsc    = (const float*)d_in[2];
  const float* smooth = (const float*)d_in[3];
  const float* pd     = (const float*)d_in[4];
  const float* pu     = (const float*)d_in[5];
  const float* bias   = (const float*)d_in[6];
  float* out = (float*)d_out;

  u16* xdq     = (u16*)d_ws;                               // 4096*3136*2 = 25.7 MB
  u16* wdq     = xdq + (size_t)MTOK * RS;                  // 3072*3136*2 = 19.3 MB
  u16* pu_bf   = wdq + (size_t)COUT * RS;                  // 3072*32*2   = 0.2 MB
  u16* lora_bf = pu_bf + (size_t)COUT * RANK;              // 4096*32*2   = 0.3 MB
  float* lp    = (float*)(lora_bf + (size_t)MTOK * RANK);  // 16*4096*32*4 = 8.4 MB

  prep_kernel<<<LORA_BLK + WDQ_BLK, 256, 0, stream>>>(
      x, smooth, qw, wsc, pd, pu, xdq, wdq, pu_bf, lp);
  lora_fix_kernel<<<MTOK * RANK / 256, 256, 0, stream>>>(lp, lora_bf);
  gemm_kernel<<<192, 512, 0, stream>>>(
      xdq, wdq, pu_bf, lora_bf, bias, out);
}